// Round 6
// baseline (278.640 us; speedup 1.0000x reference)
//
#include <hip/hip_runtime.h>
#include <hip/hip_fp16.h>

#define N_NODES 100000
#define N_EDGES 800000
// D_IN=128, D_H=64, N_CLS=40, L=4, ALPHA=0.1, THETA=0.5
// Propagated state is PRE-MULTIPLIED: h_pre[n] = dinv[n]*h[n], fp16 (64 halves = 128B/row).
// prop(h)[c] = dinv[c] * (h_pre[c] + sum_src h_pre[src]) — unweighted gather, int-only CSR.

__device__ inline float4 f4zero() { return make_float4(0.f, 0.f, 0.f, 0.f); }

__device__ inline float4 fma4(float s, float4 w, float4 a) {
    a.x = fmaf(s, w.x, a.x); a.y = fmaf(s, w.y, a.y);
    a.z = fmaf(s, w.z, a.z); a.w = fmaf(s, w.w, a.w);
    return a;
}

__device__ inline float4 relu4(float4 a) {
    a.x = fmaxf(a.x, 0.f); a.y = fmaxf(a.y, 0.f);
    a.z = fmaxf(a.z, 0.f); a.w = fmaxf(a.w, 0.f);
    return a;
}

__device__ inline float f4c(const float4& v, int i) {
    return reinterpret_cast<const float*>(&v)[i];
}

__device__ inline uint4 pack8(const float f[8]) {
    union { uint4 u; __half2 h[4]; } r;
#pragma unroll
    for (int k = 0; k < 4; ++k) r.h[k] = __floats2half2_rn(f[2 * k], f[2 * k + 1]);
    return r.u;
}

__device__ inline void unpack8(uint4 u, float f[8]) {
    union { uint4 u4; __half2 h[4]; } d; d.u4 = u;
#pragma unroll
    for (int k = 0; k < 4; ++k) { float2 t = __half22float2(d.h[k]); f[2 * k] = t.x; f[2 * k + 1] = t.y; }
}

__device__ inline uint2 pack4h(float4 v) {
    union { uint2 u; __half2 h[2]; } r;
    r.h[0] = __floats2half2_rn(v.x, v.y);
    r.h[1] = __floats2half2_rn(v.z, v.w);
    return r.u;
}

// ---------------- CSR build ----------------

__global__ __launch_bounds__(256) void k_zero_cnt(int* __restrict__ cnt) {
    int i = blockIdx.x * 256 + threadIdx.x;
    if (i < N_NODES) cnt[i] = 0;
}

__global__ __launch_bounds__(256) void k_count(const int* __restrict__ col, int* __restrict__ cnt) {
    int e = blockIdx.x * 256 + threadIdx.x;
    if (e < N_EDGES) atomicAdd(&cnt[col[e]], 1);
}

// block-wise exclusive scan: 1024 items per 256-thread block; also emits dinv and rsq=1/dinv
__global__ __launch_bounds__(256) void k_scan1(const int* __restrict__ cnt, int* __restrict__ starts,
                                               int* __restrict__ bsum, float* __restrict__ dinv,
                                               float* __restrict__ rsq) {
    __shared__ int sh[256];
    int t = threadIdx.x, b = blockIdx.x;
    int base = b * 1024 + t * 4;
    int c0 = 0, c1 = 0, c2 = 0, c3 = 0;
    if (base + 3 < N_NODES) {
        int4 v = *reinterpret_cast<const int4*>(cnt + base);
        c0 = v.x; c1 = v.y; c2 = v.z; c3 = v.w;
    } else {
        if (base + 0 < N_NODES) c0 = cnt[base + 0];
        if (base + 1 < N_NODES) c1 = cnt[base + 1];
        if (base + 2 < N_NODES) c2 = cnt[base + 2];
    }
    if (base + 0 < N_NODES) { dinv[base + 0] = rsqrtf((float)c0 + 1.f); rsq[base + 0] = sqrtf((float)c0 + 1.f); }
    if (base + 1 < N_NODES) { dinv[base + 1] = rsqrtf((float)c1 + 1.f); rsq[base + 1] = sqrtf((float)c1 + 1.f); }
    if (base + 2 < N_NODES) { dinv[base + 2] = rsqrtf((float)c2 + 1.f); rsq[base + 2] = sqrtf((float)c2 + 1.f); }
    if (base + 3 < N_NODES) { dinv[base + 3] = rsqrtf((float)c3 + 1.f); rsq[base + 3] = sqrtf((float)c3 + 1.f); }
    int s = c0 + c1 + c2 + c3;
    sh[t] = s;
    __syncthreads();
    for (int off = 1; off < 256; off <<= 1) {
        int add = (t >= off) ? sh[t - off] : 0;
        __syncthreads();
        sh[t] += add;
        __syncthreads();
    }
    int excl = sh[t] - s;
    if (t == 255) bsum[b] = sh[t];
    int p = excl;
    if (base + 0 < N_NODES) starts[base + 0] = p; p += c0;
    if (base + 1 < N_NODES) starts[base + 1] = p; p += c1;
    if (base + 2 < N_NODES) starts[base + 2] = p; p += c2;
    if (base + 3 < N_NODES) starts[base + 3] = p;
}

__global__ __launch_bounds__(128) void k_scan2(int* __restrict__ bsum, int nb) {
    __shared__ int sh[128];
    int t = threadIdx.x;
    int v = (t < nb) ? bsum[t] : 0;
    sh[t] = v;
    __syncthreads();
    for (int off = 1; off < 128; off <<= 1) {
        int add = (t >= off) ? sh[t - off] : 0;
        __syncthreads();
        sh[t] += add;
        __syncthreads();
    }
    if (t < nb) bsum[t] = sh[t] - v;
}

__global__ __launch_bounds__(256) void k_scan3(int* __restrict__ starts, int* __restrict__ cursor,
                                               const int* __restrict__ bsum) {
    int t = threadIdx.x, b = blockIdx.x;
    int off = bsum[b];
    int base = b * 1024 + t * 4;
#pragma unroll
    for (int j = 0; j < 4; ++j) {
        int i = base + j;
        if (i < N_NODES) {
            int v = starts[i] + off;
            starts[i] = v;
            cursor[i] = v;
        }
    }
    if (b == 0 && t == 0) starts[N_NODES] = N_EDGES;
}

// plain int CSR (no weights needed — h_pre is pre-multiplied)
__global__ __launch_bounds__(256) void k_fill(const int* __restrict__ row, const int* __restrict__ col,
                                              int* __restrict__ cursor, int* __restrict__ csr) {
    int e = blockIdx.x * 256 + threadIdx.x;
    if (e < N_EDGES) {
        int c = col[e];
        int p = atomicAdd(&cursor[c], 1);
        csr[p] = row[e];
    }
}

// ---------------- fc0: h_pre0 = fp16(dinv * relu(x @ W0 + b0)), 128 -> 64 ----------------
__global__ __launch_bounds__(256, 2) void k_fc0(const float* __restrict__ x, const float* __restrict__ w,
                                                const float* __restrict__ bias, const float* __restrict__ dinv,
                                                uint2* __restrict__ out) {
    __shared__ float4 ws[2048];     // W: 128 rows x 16 float4 = 32KB
    __shared__ float4 xs[64 * 33];  // x tile: 64 rows x 32 float4, pad->33
    const float4* wg = reinterpret_cast<const float4*>(w);
    const float4* x4 = reinterpret_cast<const float4*>(x);
    int tid = threadIdx.x;
    int base = blockIdx.x * 64;
#pragma unroll
    for (int i = 0; i < 8; ++i) ws[tid + 256 * i] = wg[tid + 256 * i];
#pragma unroll
    for (int j = 0; j < 8; ++j) {
        int f = tid + 256 * j;
        int ln = f >> 5, c = f & 31;
        xs[ln * 33 + c] = (base + ln < N_NODES) ? x4[(size_t)(base + ln) * 32 + c] : f4zero();
    }
    __syncthreads();
    int q = tid & 15, lbase = (tid >> 4) * 4;
    float4 bv = reinterpret_cast<const float4*>(bias)[q];
    float4 a0 = bv, a1 = bv, a2 = bv, a3 = bv;
#pragma unroll 4
    for (int kk = 0; kk < 32; ++kk) {
        float4 x0v = xs[(lbase + 0) * 33 + kk];
        float4 x1v = xs[(lbase + 1) * 33 + kk];
        float4 x2v = xs[(lbase + 2) * 33 + kk];
        float4 x3v = xs[(lbase + 3) * 33 + kk];
#pragma unroll
        for (int dk = 0; dk < 4; ++dk) {
            float4 w4 = ws[(kk * 4 + dk) * 16 + q];
            a0 = fma4(f4c(x0v, dk), w4, a0);
            a1 = fma4(f4c(x1v, dk), w4, a1);
            a2 = fma4(f4c(x2v, dk), w4, a2);
            a3 = fma4(f4c(x3v, dk), w4, a3);
        }
    }
    int n = base + lbase;
#pragma unroll
    for (int i = 0; i < 4; ++i) {
        if (n + i < N_NODES) {
            float dc = dinv[n + i];
            float4 r = relu4((i == 0) ? a0 : (i == 1) ? a1 : (i == 2) ? a2 : a3);
            r.x *= dc; r.y *= dc; r.z *= dc; r.w *= dc;
            out[(size_t)(n + i) * 16 + q] = pack4h(r);
        }
    }
}

// ---------------- 8-wide unweighted fp16 gather ----------------
__device__ __forceinline__ void gather8(const uint4* __restrict__ hp, const int* __restrict__ csr,
                                        int s, int e, int q, float acc[8]) {
    int l = e - 1;
    for (int p = s; p < e; p += 8) {
        uint4 d[8];
        float wgt[8];
#pragma unroll
        for (int j = 0; j < 8; ++j) {
            int src = csr[min(p + j, l)];
            d[j] = hp[(size_t)src * 8 + q];
            wgt[j] = (p + j <= l) ? 1.f : 0.f;
        }
#pragma unroll
        for (int j = 0; j < 8; ++j) {
            const __half2* h2 = reinterpret_cast<const __half2*>(&d[j]);
#pragma unroll
            for (int k = 0; k < 4; ++k) {
                float2 f = __half22float2(h2[k]);
                acc[2 * k]     = fmaf(wgt[j], f.x, acc[2 * k]);
                acc[2 * k + 1] = fmaf(wgt[j], f.y, acc[2 * k + 1]);
            }
        }
    }
}

// ---------------- prop0 ----------------
__global__ __launch_bounds__(256, 6) void k_prop0(const uint4* __restrict__ hp, uint4* __restrict__ x0p,
                                                  const float* __restrict__ dinv,
                                                  const int* __restrict__ starts, const int* __restrict__ csr) {
    int t = blockIdx.x * 256 + threadIdx.x;
    int node = t >> 3, q = t & 7;
    float acc[8];
    unpack8(hp[(size_t)node * 8 + q], acc);  // self term
    gather8(hp, csr, starts[node], starts[node + 1], q, acc);
    float dc = dinv[node];
    float o[8];
#pragma unroll
    for (int k = 0; k < 8; ++k) o[k] = dc * fmaxf(dc * acc[k], 0.f);
    x0p[(size_t)node * 8 + q] = pack8(o);
}

// ---------------- fused: prop + alpha-combine + conv [+ fc1] ----------------
// 256 threads = 32 nodes x 8 lanes; lane owns 8 feature cols (q*8..q*8+7).
// Cross-lane m distribution via __shfl within the 8-lane group (no LDS tile -> high occupancy).
template <bool FINAL>
__global__ __launch_bounds__(256, FINAL ? 4 : 6) void k_propconv(
    const uint4* __restrict__ hp_in, const uint4* __restrict__ x0p,
    const float* __restrict__ dinv, const float* __restrict__ rsq,
    const int* __restrict__ starts, const int* __restrict__ csr,
    const float* __restrict__ w, float beta,
    const float* __restrict__ w1, const float* __restrict__ b1,
    void* __restrict__ out) {
    __shared__ float ws[64 * 64];                        // conv W row-major [k][c], 16KB
    __shared__ float hs[FINAL ? 32 : 1][FINAL ? 65 : 1]; // conv out tile (FINAL only)
    __shared__ float ws1[FINAL ? 64 * 41 : 1];           // fc1 W (FINAL only)

    int tid = threadIdx.x;
    int nl = tid >> 3, q = tid & 7;
    int node = blockIdx.x * 32 + nl;

    // stage weights early; loads complete under the gather
    const float4* wg = reinterpret_cast<const float4*>(w);
    float4* wsv = reinterpret_cast<float4*>(ws);
#pragma unroll
    for (int i = 0; i < 4; ++i) wsv[tid + 256 * i] = wg[tid + 256 * i];
    if constexpr (FINAL) {
        for (int i = tid; i < 64 * 40; i += 256) {
            int k = i / 40, c = i - k * 40;
            ws1[k * 41 + c] = w1[i];
        }
    }

    float acc[8];
    unpack8(hp_in[(size_t)node * 8 + q], acc);  // self term
    gather8(hp_in, csr, starts[node], starts[node + 1], q, acc);

    float dc = dinv[node];
    float rs = rsq[node];
    float xq[8];
    unpack8(x0p[(size_t)node * 8 + q], xq);
    float m[8];
#pragma unroll
    for (int k = 0; k < 8; ++k) m[k] = 0.9f * dc * acc[k] + 0.1f * rs * xq[k];

    __syncthreads();  // ws (and ws1) visible

    // conv: a[c] = sum_k m[k] * W[k][c]; m[k] fetched from owner lane via shfl (width 8)
    float a[8] = {0.f, 0.f, 0.f, 0.f, 0.f, 0.f, 0.f, 0.f};
#pragma unroll
    for (int src = 0; src < 8; ++src) {
        float mv[8];
#pragma unroll
        for (int j = 0; j < 8; ++j) mv[j] = __shfl(m[j], src, 8);
#pragma unroll
        for (int j = 0; j < 8; ++j) {
            int k = src * 8 + j;
            float4 wv0 = *reinterpret_cast<const float4*>(&ws[k * 64 + q * 8]);
            float4 wv1 = *reinterpret_cast<const float4*>(&ws[k * 64 + q * 8 + 4]);
            a[0] = fmaf(mv[j], wv0.x, a[0]); a[1] = fmaf(mv[j], wv0.y, a[1]);
            a[2] = fmaf(mv[j], wv0.z, a[2]); a[3] = fmaf(mv[j], wv0.w, a[3]);
            a[4] = fmaf(mv[j], wv1.x, a[4]); a[5] = fmaf(mv[j], wv1.y, a[5]);
            a[6] = fmaf(mv[j], wv1.z, a[6]); a[7] = fmaf(mv[j], wv1.w, a[7]);
        }
    }
    float omb = 1.f - beta;
    float r[8];
#pragma unroll
    for (int k = 0; k < 8; ++k) r[k] = fmaxf(fmaf(omb, m[k], beta * a[k]), 0.f);

    if constexpr (!FINAL) {
        float o[8];
#pragma unroll
        for (int k = 0; k < 8; ++k) o[k] = dc * r[k];
        reinterpret_cast<uint4*>(out)[(size_t)node * 8 + q] = pack8(o);
    } else {
#pragma unroll
        for (int k = 0; k < 8; ++k) hs[nl][q * 8 + k] = r[k];
        __syncthreads();
        float acc1[5];
#pragma unroll
        for (int j = 0; j < 5; ++j) acc1[j] = b1[q * 5 + j];
#pragma unroll 8
        for (int k = 0; k < 64; ++k) {
            float hv = hs[nl][k];
#pragma unroll
            for (int j = 0; j < 5; ++j) acc1[j] = fmaf(hv, ws1[k * 41 + q * 5 + j], acc1[j]);
        }
        float* o = reinterpret_cast<float*>(out) + (size_t)node * 40 + q * 5;
#pragma unroll
        for (int j = 0; j < 5; ++j) o[j] = acc1[j];
    }
}

// ---------------- launch ----------------

extern "C" void kernel_launch(void* const* d_in, const int* in_sizes, int n_in,
                              void* d_out, int out_size, void* d_ws, size_t ws_size,
                              hipStream_t stream) {
    const float* x      = (const float*)d_in[0];
    const int*   ei     = (const int*)d_in[1];
    const float* fc0_w  = (const float*)d_in[2];
    const float* fc0_b  = (const float*)d_in[3];
    const float* fc1_w  = (const float*)d_in[4];
    const float* fc1_b  = (const float*)d_in[5];
    const float* conv_w = (const float*)d_in[6];
    const int* row = ei;
    const int* col = ei + N_EDGES;

    char* ws = (char*)d_ws;
    size_t off = 0;
    auto alloc = [&](size_t bytes) -> void* {
        void* p = ws + off;
        off += (bytes + 255) & ~(size_t)255;
        return p;
    };
    float* dinv   = (float*)alloc((size_t)N_NODES * 4);
    float* rsq    = (float*)alloc((size_t)N_NODES * 4);
    int*   cnt    = (int*)alloc((size_t)N_NODES * 4);
    int*   starts = (int*)alloc((size_t)(N_NODES + 1) * 4);
    int*   cursor = (int*)alloc((size_t)(N_NODES + 1) * 4);
    int*   csr    = (int*)alloc((size_t)N_EDGES * 4);
    int*   bsum   = (int*)alloc(128 * 4);
    uint4* hp0    = (uint4*)alloc((size_t)N_NODES * 128);  // fp16 h_pre, 128B/row
    uint4* x0p    = (uint4*)alloc((size_t)N_NODES * 128);
    uint4* hpA    = (uint4*)alloc((size_t)N_NODES * 128);
    uint4* hpB    = (uint4*)alloc((size_t)N_NODES * 128);
    if (off > ws_size) return;

    const int NB1 = (N_NODES + 1023) / 1024;          // 98
    const int GN  = (N_NODES + 255) / 256;            // 391
    const int GE  = (N_EDGES + 255) / 256;            // 3125
    const int GMM = (N_NODES + 63) / 64;              // 1563 (fc0)
    const int GP  = (N_NODES * 8) / 256;              // 3125 (prop0: 8 lanes/node)
    const int GPC = N_NODES / 32;                     // 3125 (propconv: 32 nodes/block)

    // CSR build + degree
    k_zero_cnt<<<GN, 256, 0, stream>>>(cnt);
    k_count<<<GE, 256, 0, stream>>>(col, cnt);
    k_scan1<<<NB1, 256, 0, stream>>>(cnt, starts, bsum, dinv, rsq);
    k_scan2<<<1, 128, 0, stream>>>(bsum, NB1);
    k_scan3<<<NB1, 256, 0, stream>>>(starts, cursor, bsum);
    k_fill<<<GE, 256, 0, stream>>>(row, col, cursor, csr);

    // fc0 -> hp0 (fp16 pre-multiplied); prop0 -> x0p
    k_fc0<<<GMM, 256, 0, stream>>>(x, fc0_w, fc0_b, dinv, (uint2*)hp0);
    k_prop0<<<GP, 256, 0, stream>>>(hp0, x0p, dinv, starts, csr);

    const float betas[4] = {0.f, logf(0.5f / 2.f + 1.f), logf(0.5f / 3.f + 1.f), logf(0.5f / 4.f + 1.f)};

    // layer 1: x0p -> hpA ; layer 2: hpA -> hpB ; layer 3 (+fc1): hpB -> d_out
    k_propconv<false><<<GPC, 256, 0, stream>>>(x0p, x0p, dinv, rsq, starts, csr,
                                               conv_w + 1 * 4096, betas[1], nullptr, nullptr, hpA);
    k_propconv<false><<<GPC, 256, 0, stream>>>(hpA, x0p, dinv, rsq, starts, csr,
                                               conv_w + 2 * 4096, betas[2], nullptr, nullptr, hpB);
    k_propconv<true><<<GPC, 256, 0, stream>>>(hpB, x0p, dinv, rsq, starts, csr,
                                              conv_w + 3 * 4096, betas[3], fc1_w, fc1_b, d_out);
}

// Round 7
// 224.107 us; speedup vs baseline: 1.2433x; 1.2433x over previous
//
#include <hip/hip_runtime.h>
#include <hip/hip_fp16.h>

#define N_NODES 100000
#define N_EDGES 800000
// D_IN=128, D_H=64, N_CLS=40, L=4, ALPHA=0.1, THETA=0.5
// State PRE-MULTIPLIED: h_pre[n] = dinv[n]*h[n], fp16 (64 halves = 128B/row).
// prop(h)[c] = dinv[c] * (h_pre[c] + sum_src h_pre[src]) — unweighted gather, int CSR.
// All dense math in fp16-input / fp32-accum dot2; weights pre-paired by k_wcvt.

__device__ inline float4 f4zero() { return make_float4(0.f, 0.f, 0.f, 0.f); }

__device__ inline unsigned pack2u(float a, float b) {
    union { unsigned u; __half2 h; } r; r.h = __floats2half2_rn(a, b); return r.u;
}
__device__ inline float2 unpack2f(unsigned u) {
    union { unsigned uu; __half2 h; } d; d.uu = u; return __half22float2(d.h);
}

typedef _Float16 hf2 __attribute__((ext_vector_type(2)));
__device__ inline float fdot2(unsigned a, unsigned b, float c) {
#if __has_builtin(__builtin_amdgcn_fdot2)
    union { unsigned u; hf2 h; } ua, ub; ua.u = a; ub.u = b;
    return __builtin_amdgcn_fdot2(ua.h, ub.h, c, false);
#else
    float2 fa = unpack2f(a), fb = unpack2f(b);
    return fmaf(fa.x, fb.x, fmaf(fa.y, fb.y, c));
#endif
}

__device__ inline uint4 pack8(const float f[8]) {
    uint4 u;
    u.x = pack2u(f[0], f[1]); u.y = pack2u(f[2], f[3]);
    u.z = pack2u(f[4], f[5]); u.w = pack2u(f[6], f[7]);
    return u;
}
__device__ inline void unpack8(uint4 u, float f[8]) {
    float2 t;
    t = unpack2f(u.x); f[0] = t.x; f[1] = t.y;
    t = unpack2f(u.y); f[2] = t.x; f[3] = t.y;
    t = unpack2f(u.z); f[4] = t.x; f[5] = t.y;
    t = unpack2f(u.w); f[6] = t.x; f[7] = t.y;
}

// ---------------- CSR build ----------------

__global__ __launch_bounds__(256) void k_zero_cnt(int* __restrict__ cnt) {
    int i = blockIdx.x * 256 + threadIdx.x;
    if (i < N_NODES) cnt[i] = 0;
}

__global__ __launch_bounds__(256) void k_count(const int* __restrict__ col, int* __restrict__ cnt) {
    int e = blockIdx.x * 256 + threadIdx.x;
    if (e < N_EDGES) atomicAdd(&cnt[col[e]], 1);
}

__global__ __launch_bounds__(256) void k_scan1(const int* __restrict__ cnt, int* __restrict__ starts,
                                               int* __restrict__ bsum, float* __restrict__ dinv,
                                               float* __restrict__ rsq) {
    __shared__ int sh[256];
    int t = threadIdx.x, b = blockIdx.x;
    int base = b * 1024 + t * 4;
    int c0 = 0, c1 = 0, c2 = 0, c3 = 0;
    if (base + 3 < N_NODES) {
        int4 v = *reinterpret_cast<const int4*>(cnt + base);
        c0 = v.x; c1 = v.y; c2 = v.z; c3 = v.w;
    } else {
        if (base + 0 < N_NODES) c0 = cnt[base + 0];
        if (base + 1 < N_NODES) c1 = cnt[base + 1];
        if (base + 2 < N_NODES) c2 = cnt[base + 2];
    }
    if (base + 0 < N_NODES) { dinv[base + 0] = rsqrtf((float)c0 + 1.f); rsq[base + 0] = sqrtf((float)c0 + 1.f); }
    if (base + 1 < N_NODES) { dinv[base + 1] = rsqrtf((float)c1 + 1.f); rsq[base + 1] = sqrtf((float)c1 + 1.f); }
    if (base + 2 < N_NODES) { dinv[base + 2] = rsqrtf((float)c2 + 1.f); rsq[base + 2] = sqrtf((float)c2 + 1.f); }
    if (base + 3 < N_NODES) { dinv[base + 3] = rsqrtf((float)c3 + 1.f); rsq[base + 3] = sqrtf((float)c3 + 1.f); }
    int s = c0 + c1 + c2 + c3;
    sh[t] = s;
    __syncthreads();
    for (int off = 1; off < 256; off <<= 1) {
        int add = (t >= off) ? sh[t - off] : 0;
        __syncthreads();
        sh[t] += add;
        __syncthreads();
    }
    int excl = sh[t] - s;
    if (t == 255) bsum[b] = sh[t];
    int p = excl;
    if (base + 0 < N_NODES) starts[base + 0] = p; p += c0;
    if (base + 1 < N_NODES) starts[base + 1] = p; p += c1;
    if (base + 2 < N_NODES) starts[base + 2] = p; p += c2;
    if (base + 3 < N_NODES) starts[base + 3] = p;
}

__global__ __launch_bounds__(128) void k_scan2(int* __restrict__ bsum, int nb) {
    __shared__ int sh[128];
    int t = threadIdx.x;
    int v = (t < nb) ? bsum[t] : 0;
    sh[t] = v;
    __syncthreads();
    for (int off = 1; off < 128; off <<= 1) {
        int add = (t >= off) ? sh[t - off] : 0;
        __syncthreads();
        sh[t] += add;
        __syncthreads();
    }
    if (t < nb) bsum[t] = sh[t] - v;
}

__global__ __launch_bounds__(256) void k_scan3(int* __restrict__ starts, int* __restrict__ cursor,
                                               const int* __restrict__ bsum) {
    int t = threadIdx.x, b = blockIdx.x;
    int off = bsum[b];
    int base = b * 1024 + t * 4;
#pragma unroll
    for (int j = 0; j < 4; ++j) {
        int i = base + j;
        if (i < N_NODES) {
            int v = starts[i] + off;
            starts[i] = v;
            cursor[i] = v;
        }
    }
    if (b == 0 && t == 0) starts[N_NODES] = N_EDGES;
}

__global__ __launch_bounds__(256) void k_fill(const int* __restrict__ row, const int* __restrict__ col,
                                              int* __restrict__ cursor, int* __restrict__ csr) {
    int e = blockIdx.x * 256 + threadIdx.x;
    if (e < N_EDGES) {
        int c = col[e];
        int p = atomicAdd(&cursor[c], 1);
        csr[p] = row[e];
    }
}

// ---------------- weight conversion: fp32 -> k-paired half2 ----------------
// wh  (conv layers 1..3): wh[layer*2048 + kp*64 + c] = {W[2kp][c], W[2kp+1][c]}, kp<32, c<64
// w1h (fc1): w1h[kp*40 + c] = {W1[2kp][c], W1[2kp+1][c]}, kp<32, c<40
// w0h (fc0): w0h[kp*64 + c] = {W0[2kp][c], W0[2kp+1][c]}, kp<64, c<64
__global__ __launch_bounds__(256) void k_wcvt(const float* __restrict__ conv_w, const float* __restrict__ fc1_w,
                                              const float* __restrict__ fc0_w,
                                              unsigned* __restrict__ wh, unsigned* __restrict__ w1h,
                                              unsigned* __restrict__ w0h) {
    int i = blockIdx.x * 256 + threadIdx.x;
    if (i < 3 * 2048) {
        int layer = i >> 11, rem = i & 2047, kp = rem >> 6, c = rem & 63;
        const float* wsrc = conv_w + (size_t)(layer + 1) * 4096;
        wh[i] = pack2u(wsrc[(2 * kp) * 64 + c], wsrc[(2 * kp + 1) * 64 + c]);
        return;
    }
    int j = i - 3 * 2048;
    if (j < 1280) {
        int kp = j / 40, c = j - kp * 40;
        w1h[j] = pack2u(fc1_w[(2 * kp) * 40 + c], fc1_w[(2 * kp + 1) * 40 + c]);
        return;
    }
    int t = j - 1280;
    if (t < 4096) {
        int kp = t >> 6, c = t & 63;
        w0h[t] = pack2u(fc0_w[(2 * kp) * 64 + c], fc0_w[(2 * kp + 1) * 64 + c]);
    }
}

// ---------------- fc0: h_pre0 = fp16(dinv * relu(x @ W0 + b0)), 128 -> 64, dot2 ----------------
// 256 threads = 64 nodes; thread: 4 nodes x 4 cols
__global__ __launch_bounds__(256, 4) void k_fc0(const float* __restrict__ x, const unsigned* __restrict__ w0h,
                                                const float* __restrict__ bias, const float* __restrict__ dinv,
                                                uint2* __restrict__ out) {
    __shared__ unsigned wsh[64 * 64];   // 16KB
    __shared__ unsigned xs2[64 * 65];   // 16.6KB, pad 65
    const float4* x4 = reinterpret_cast<const float4*>(x);
    int tid = threadIdx.x;
    int base = blockIdx.x * 64;
#pragma unroll
    for (int i = 0; i < 4; ++i)
        reinterpret_cast<uint4*>(wsh)[tid + 256 * i] = reinterpret_cast<const uint4*>(w0h)[tid + 256 * i];
#pragma unroll
    for (int j = 0; j < 8; ++j) {
        int f = tid + 256 * j;          // 0..2047
        int ln = f >> 5, c = f & 31;    // c-th float4 of row ln
        float4 v = (base + ln < N_NODES) ? x4[(size_t)(base + ln) * 32 + c] : f4zero();
        xs2[ln * 65 + 2 * c]     = pack2u(v.x, v.y);
        xs2[ln * 65 + 2 * c + 1] = pack2u(v.z, v.w);
    }
    __syncthreads();
    int q = tid & 15, lbase = (tid >> 4) * 4;
    float4 bv = reinterpret_cast<const float4*>(bias)[q];
    float a[4][4];
#pragma unroll
    for (int n = 0; n < 4; ++n) { a[n][0] = bv.x; a[n][1] = bv.y; a[n][2] = bv.z; a[n][3] = bv.w; }
#pragma unroll 4
    for (int kp = 0; kp < 64; ++kp) {
        unsigned xh0 = xs2[(lbase + 0) * 65 + kp];
        unsigned xh1 = xs2[(lbase + 1) * 65 + kp];
        unsigned xh2 = xs2[(lbase + 2) * 65 + kp];
        unsigned xh3 = xs2[(lbase + 3) * 65 + kp];
        uint4 wv = *reinterpret_cast<const uint4*>(&wsh[kp * 64 + q * 4]);
        a[0][0] = fdot2(xh0, wv.x, a[0][0]); a[0][1] = fdot2(xh0, wv.y, a[0][1]);
        a[0][2] = fdot2(xh0, wv.z, a[0][2]); a[0][3] = fdot2(xh0, wv.w, a[0][3]);
        a[1][0] = fdot2(xh1, wv.x, a[1][0]); a[1][1] = fdot2(xh1, wv.y, a[1][1]);
        a[1][2] = fdot2(xh1, wv.z, a[1][2]); a[1][3] = fdot2(xh1, wv.w, a[1][3]);
        a[2][0] = fdot2(xh2, wv.x, a[2][0]); a[2][1] = fdot2(xh2, wv.y, a[2][1]);
        a[2][2] = fdot2(xh2, wv.z, a[2][2]); a[2][3] = fdot2(xh2, wv.w, a[2][3]);
        a[3][0] = fdot2(xh3, wv.x, a[3][0]); a[3][1] = fdot2(xh3, wv.y, a[3][1]);
        a[3][2] = fdot2(xh3, wv.z, a[3][2]); a[3][3] = fdot2(xh3, wv.w, a[3][3]);
    }
#pragma unroll
    for (int n = 0; n < 4; ++n) {
        int nn = base + lbase + n;
        if (nn < N_NODES) {
            float dc = dinv[nn];
            float r0 = dc * fmaxf(a[n][0], 0.f), r1 = dc * fmaxf(a[n][1], 0.f);
            float r2 = dc * fmaxf(a[n][2], 0.f), r3 = dc * fmaxf(a[n][3], 0.f);
            uint2 u; u.x = pack2u(r0, r1); u.y = pack2u(r2, r3);
            out[(size_t)nn * 16 + q] = u;
        }
    }
}

// ---------------- packed fp16 gather (4 pk_fma/edge) with csr prefetch ----------------
__device__ __forceinline__ void gather8h(const uint4* __restrict__ hp, const int* __restrict__ csr,
                                         int s, int e, int q, __half2 acc2[4]) {
    if (s >= e) return;
    int l = e - 1;
    int idx[8];
#pragma unroll
    for (int j = 0; j < 8; ++j) idx[j] = csr[min(s + j, l)];
    for (int p = s; p < e; p += 8) {
        uint4 d[8];
        unsigned msk[8];
#pragma unroll
        for (int j = 0; j < 8; ++j) {
            d[j] = hp[(size_t)idx[j] * 8 + q];
            msk[j] = (p + j <= l) ? 0x3C003C00u : 0u;  // half2{1,1} : {0,0}
        }
        if (p + 8 < e) {
#pragma unroll
            for (int j = 0; j < 8; ++j) idx[j] = csr[min(p + 8 + j, l)];
        }
#pragma unroll
        for (int j = 0; j < 8; ++j) {
            __half2 w2 = *reinterpret_cast<__half2*>(&msk[j]);
            const __half2* h2 = reinterpret_cast<const __half2*>(&d[j]);
            acc2[0] = __hfma2(w2, h2[0], acc2[0]);
            acc2[1] = __hfma2(w2, h2[1], acc2[1]);
            acc2[2] = __hfma2(w2, h2[2], acc2[2]);
            acc2[3] = __hfma2(w2, h2[3], acc2[3]);
        }
    }
}

// ---------------- prop0 ----------------
__global__ __launch_bounds__(256, 6) void k_prop0(const uint4* __restrict__ hp, uint4* __restrict__ x0p,
                                                  const float* __restrict__ dinv,
                                                  const int* __restrict__ starts, const int* __restrict__ csr) {
    int t = blockIdx.x * 256 + threadIdx.x;
    int node = t >> 3, q = t & 7;
    uint4 self = hp[(size_t)node * 8 + q];
    __half2 acc2[4];
    const __half2* sh2 = reinterpret_cast<const __half2*>(&self);
#pragma unroll
    for (int k = 0; k < 4; ++k) acc2[k] = sh2[k];
    gather8h(hp, csr, starts[node], starts[node + 1], q, acc2);
    float dc = dinv[node];
    float accf[8];
    unpack8(*reinterpret_cast<uint4*>(acc2), accf);
    float o[8];
#pragma unroll
    for (int k = 0; k < 8; ++k) o[k] = dc * fmaxf(dc * accf[k], 0.f);
    x0p[(size_t)node * 8 + q] = pack8(o);
}

// ---------------- fused: prop + alpha-combine + conv [+ fc1], all dot2 ----------------
// 256 threads = 32 nodes x 8 lanes; lane owns 8 feature cols (q*8..q*8+7)
template <bool FINAL>
__global__ __launch_bounds__(256, 6) void k_propconv(
    const uint4* __restrict__ hp_in, const uint4* __restrict__ x0p,
    const float* __restrict__ dinv, const float* __restrict__ rsq,
    const int* __restrict__ starts, const int* __restrict__ csr,
    const unsigned* __restrict__ wh, float beta,
    const unsigned* __restrict__ w1h, const float* __restrict__ b1,
    void* __restrict__ out) {
    __shared__ unsigned ws2[32 * 64];                 // 8KB: paired conv W [kp][c]
    __shared__ unsigned ws12[FINAL ? 32 * 40 : 1];    // 5KB: paired fc1 W (FINAL)

    int tid = threadIdx.x;
    int nl = tid >> 3, q = tid & 7;
    int node = blockIdx.x * 32 + nl;

    // stage weights early (complete under the gather)
    reinterpret_cast<uint4*>(ws2)[tid]       = reinterpret_cast<const uint4*>(wh)[tid];
    reinterpret_cast<uint4*>(ws2)[tid + 256] = reinterpret_cast<const uint4*>(wh)[tid + 256];
    if constexpr (FINAL) {
        reinterpret_cast<uint4*>(ws12)[tid < 320 ? tid : 0] = reinterpret_cast<const uint4*>(w1h)[tid < 320 ? tid : 0];
        if (tid < 64) reinterpret_cast<uint4*>(ws12)[tid + 256] = reinterpret_cast<const uint4*>(w1h)[tid + 256];
    }

    uint4 self = hp_in[(size_t)node * 8 + q];
    __half2 acc2[4];
    const __half2* sh2 = reinterpret_cast<const __half2*>(&self);
#pragma unroll
    for (int k = 0; k < 4; ++k) acc2[k] = sh2[k];
    gather8h(hp_in, csr, starts[node], starts[node + 1], q, acc2);

    float dc = dinv[node];
    float rs = rsq[node];
    float accf[8], xq[8];
    unpack8(*reinterpret_cast<uint4*>(acc2), accf);
    unpack8(x0p[(size_t)node * 8 + q], xq);
    float m[8];
#pragma unroll
    for (int k = 0; k < 8; ++k) m[k] = 0.9f * dc * accf[k] + 0.1f * rs * xq[k];
    unsigned mh[4];
#pragma unroll
    for (int t = 0; t < 4; ++t) mh[t] = pack2u(m[2 * t], m[2 * t + 1]);

    __syncthreads();  // weights visible

    // conv: a[c] = sum_k m[k]*W[k][c] via dot2; m fetched from owner lane via shfl(width 8)
    float a[8] = {0.f, 0.f, 0.f, 0.f, 0.f, 0.f, 0.f, 0.f};
#pragma unroll
    for (int src = 0; src < 8; ++src) {
        unsigned mm[4];
#pragma unroll
        for (int t = 0; t < 4; ++t) mm[t] = (unsigned)__shfl((int)mh[t], src, 8);
#pragma unroll
        for (int t = 0; t < 4; ++t) {
            int kp = src * 4 + t;
            const uint4* wr = reinterpret_cast<const uint4*>(&ws2[kp * 64 + q * 8]);
            uint4 w0 = wr[0], w1 = wr[1];
            a[0] = fdot2(mm[t], w0.x, a[0]); a[1] = fdot2(mm[t], w0.y, a[1]);
            a[2] = fdot2(mm[t], w0.z, a[2]); a[3] = fdot2(mm[t], w0.w, a[3]);
            a[4] = fdot2(mm[t], w1.x, a[4]); a[5] = fdot2(mm[t], w1.y, a[5]);
            a[6] = fdot2(mm[t], w1.z, a[6]); a[7] = fdot2(mm[t], w1.w, a[7]);
        }
    }
    float omb = 1.f - beta;
    float r[8];
#pragma unroll
    for (int k = 0; k < 8; ++k) r[k] = fmaxf(fmaf(omb, m[k], beta * a[k]), 0.f);

    if constexpr (!FINAL) {
        float o[8];
#pragma unroll
        for (int k = 0; k < 8; ++k) o[k] = dc * r[k];
        reinterpret_cast<uint4*>(out)[(size_t)node * 8 + q] = pack8(o);
    } else {
        // fc1 via the same shuffle+dot2 trick (no LDS tile)
        unsigned rh[4];
#pragma unroll
        for (int t = 0; t < 4; ++t) rh[t] = pack2u(r[2 * t], r[2 * t + 1]);
        float acc1[5];
#pragma unroll
        for (int j = 0; j < 5; ++j) acc1[j] = b1[q * 5 + j];
#pragma unroll
        for (int src = 0; src < 8; ++src) {
            unsigned rm[4];
#pragma unroll
            for (int t = 0; t < 4; ++t) rm[t] = (unsigned)__shfl((int)rh[t], src, 8);
#pragma unroll
            for (int t = 0; t < 4; ++t) {
                int kp = src * 4 + t;
                const unsigned* wr = &ws12[kp * 40 + q * 5];
#pragma unroll
                for (int j = 0; j < 5; ++j) acc1[j] = fdot2(rm[t], wr[j], acc1[j]);
            }
        }
        float* o = reinterpret_cast<float*>(out) + (size_t)node * 40 + q * 5;
#pragma unroll
        for (int j = 0; j < 5; ++j) o[j] = acc1[j];
    }
}

// ---------------- launch ----------------

extern "C" void kernel_launch(void* const* d_in, const int* in_sizes, int n_in,
                              void* d_out, int out_size, void* d_ws, size_t ws_size,
                              hipStream_t stream) {
    const float* x      = (const float*)d_in[0];
    const int*   ei     = (const int*)d_in[1];
    const float* fc0_w  = (const float*)d_in[2];
    const float* fc0_b  = (const float*)d_in[3];
    const float* fc1_w  = (const float*)d_in[4];
    const float* fc1_b  = (const float*)d_in[5];
    const float* conv_w = (const float*)d_in[6];
    const int* row = ei;
    const int* col = ei + N_EDGES;

    char* ws = (char*)d_ws;
    size_t off = 0;
    auto alloc = [&](size_t bytes) -> void* {
        void* p = ws + off;
        off += (bytes + 255) & ~(size_t)255;
        return p;
    };
    float*    dinv   = (float*)alloc((size_t)N_NODES * 4);
    float*    rsq    = (float*)alloc((size_t)N_NODES * 4);
    int*      cnt    = (int*)alloc((size_t)N_NODES * 4);
    int*      starts = (int*)alloc((size_t)(N_NODES + 1) * 4);
    int*      cursor = (int*)alloc((size_t)(N_NODES + 1) * 4);
    int*      csr    = (int*)alloc((size_t)N_EDGES * 4);
    int*      bsum   = (int*)alloc(128 * 4);
    unsigned* wh     = (unsigned*)alloc(3 * 2048 * 4);
    unsigned* w1h    = (unsigned*)alloc(1280 * 4);
    unsigned* w0h    = (unsigned*)alloc(4096 * 4);
    uint4*    hp0    = (uint4*)alloc((size_t)N_NODES * 128);
    uint4*    x0p    = (uint4*)alloc((size_t)N_NODES * 128);
    uint4*    hpA    = (uint4*)alloc((size_t)N_NODES * 128);
    uint4*    hpB    = (uint4*)alloc((size_t)N_NODES * 128);
    if (off > ws_size) return;

    const int NB1 = (N_NODES + 1023) / 1024;          // 98
    const int GN  = (N_NODES + 255) / 256;            // 391
    const int GE  = (N_EDGES + 255) / 256;            // 3125
    const int GMM = (N_NODES + 63) / 64;              // 1563 (fc0)
    const int GP  = (N_NODES * 8) / 256;              // 3125 (prop0)
    const int GPC = N_NODES / 32;                     // 3125 (propconv)

    // weight conversion (independent) + CSR build
    k_wcvt<<<45, 256, 0, stream>>>(conv_w, fc1_w, fc0_w, wh, w1h, w0h);
    k_zero_cnt<<<GN, 256, 0, stream>>>(cnt);
    k_count<<<GE, 256, 0, stream>>>(col, cnt);
    k_scan1<<<NB1, 256, 0, stream>>>(cnt, starts, bsum, dinv, rsq);
    k_scan2<<<1, 128, 0, stream>>>(bsum, NB1);
    k_scan3<<<NB1, 256, 0, stream>>>(starts, cursor, bsum);
    k_fill<<<GE, 256, 0, stream>>>(row, col, cursor, csr);

    // fc0 -> hp0; prop0 -> x0p
    k_fc0<<<GMM, 256, 0, stream>>>(x, w0h, fc0_b, dinv, (uint2*)hp0);
    k_prop0<<<GP, 256, 0, stream>>>(hp0, x0p, dinv, starts, csr);

    const float betas[4] = {0.f, logf(0.5f / 2.f + 1.f), logf(0.5f / 3.f + 1.f), logf(0.5f / 4.f + 1.f)};

    // layer 1: x0p -> hpA ; layer 2: hpA -> hpB ; layer 3 (+fc1): hpB -> d_out
    k_propconv<false><<<GPC, 256, 0, stream>>>(x0p, x0p, dinv, rsq, starts, csr,
                                               wh + 0 * 2048, betas[1], nullptr, nullptr, hpA);
    k_propconv<false><<<GPC, 256, 0, stream>>>(hpA, x0p, dinv, rsq, starts, csr,
                                               wh + 1 * 2048, betas[2], nullptr, nullptr, hpB);
    k_propconv<true><<<GPC, 256, 0, stream>>>(hpB, x0p, dinv, rsq, starts, csr,
                                              wh + 2 * 2048, betas[3], w1h, fc1_b, d_out);
}

// Round 8
// 158.003 us; speedup vs baseline: 1.7635x; 1.4184x over previous
//
#include <hip/hip_runtime.h>
#include <hip/hip_fp16.h>

#define N_NODES 100000
#define N_EDGES 800000
#define N_BUCKET 391              // ceil(100000/256)
#define L_HIST (N_BUCKET * 256)   // 100096
// D_IN=128, D_H=64, N_CLS=40, L=4, ALPHA=0.1, THETA=0.5
// State PRE-MULTIPLIED: h_pre[n] = dinv[n]*h[n], fp16 (64 halves = 128B/row).
// prop(h)[c] = dinv[c] * (h_pre[c] + sum_src h_pre[src]) — unweighted gather, int CSR.
// CSR built via MSD bucket sort (col>>8 then col&255) — clustered writes, no scattered 4B stores.

__device__ inline float4 f4zero() { return make_float4(0.f, 0.f, 0.f, 0.f); }

__device__ inline unsigned pack2u(float a, float b) {
    union { unsigned u; __half2 h; } r; r.h = __floats2half2_rn(a, b); return r.u;
}
__device__ inline float2 unpack2f(unsigned u) {
    union { unsigned uu; __half2 h; } d; d.uu = u; return __half22float2(d.h);
}

typedef _Float16 hf2 __attribute__((ext_vector_type(2)));
__device__ inline float fdot2(unsigned a, unsigned b, float c) {
#if __has_builtin(__builtin_amdgcn_fdot2)
    union { unsigned u; hf2 h; } ua, ub; ua.u = a; ub.u = b;
    return __builtin_amdgcn_fdot2(ua.h, ub.h, c, false);
#else
    float2 fa = unpack2f(a), fb = unpack2f(b);
    return fmaf(fa.x, fb.x, fmaf(fa.y, fb.y, c));
#endif
}

__device__ inline uint4 pack8(const float f[8]) {
    uint4 u;
    u.x = pack2u(f[0], f[1]); u.y = pack2u(f[2], f[3]);
    u.z = pack2u(f[4], f[5]); u.w = pack2u(f[6], f[7]);
    return u;
}
__device__ inline void unpack8(uint4 u, float f[8]) {
    float2 t;
    t = unpack2f(u.x); f[0] = t.x; f[1] = t.y;
    t = unpack2f(u.y); f[2] = t.x; f[3] = t.y;
    t = unpack2f(u.z); f[4] = t.x; f[5] = t.y;
    t = unpack2f(u.w); f[6] = t.x; f[7] = t.y;
}

// ---------------- CSR build via MSD bucket sort ----------------

// pass-1 histogram: 256 blocks x 3125 edges; transposed output histT[d*256 + b]
__global__ __launch_bounds__(256) void k_hist(const int* __restrict__ col, int* __restrict__ histT) {
    __shared__ int hist[N_BUCKET];
    int b = blockIdx.x, t = threadIdx.x;
    for (int i = t; i < N_BUCKET; i += 256) hist[i] = 0;
    __syncthreads();
    const int base = b * 3125;
    for (int i = t; i < 3125; i += 256) atomicAdd(&hist[col[base + i] >> 8], 1);
    __syncthreads();
    for (int d = t; d < N_BUCKET; d += 256) histT[d * 256 + b] = hist[d];
}

// generic 3-kernel exclusive scan over L ints (L = 100096 here)
__global__ __launch_bounds__(256) void k_scanA(const int* __restrict__ in, int* __restrict__ out,
                                               int* __restrict__ bsum, int L) {
    __shared__ int sh[256];
    int t = threadIdx.x, b = blockIdx.x;
    int base = b * 1024 + t * 4;
    int c0 = 0, c1 = 0, c2 = 0, c3 = 0;
    if (base + 3 < L) {
        int4 v = *reinterpret_cast<const int4*>(in + base);
        c0 = v.x; c1 = v.y; c2 = v.z; c3 = v.w;
    } else {
        if (base + 0 < L) c0 = in[base + 0];
        if (base + 1 < L) c1 = in[base + 1];
        if (base + 2 < L) c2 = in[base + 2];
    }
    int s = c0 + c1 + c2 + c3;
    sh[t] = s;
    __syncthreads();
    for (int off = 1; off < 256; off <<= 1) {
        int add = (t >= off) ? sh[t - off] : 0;
        __syncthreads();
        sh[t] += add;
        __syncthreads();
    }
    int excl = sh[t] - s;
    if (t == 255) bsum[b] = sh[t];
    int p = excl;
    if (base + 0 < L) out[base + 0] = p; p += c0;
    if (base + 1 < L) out[base + 1] = p; p += c1;
    if (base + 2 < L) out[base + 2] = p; p += c2;
    if (base + 3 < L) out[base + 3] = p;
}

__global__ __launch_bounds__(128) void k_scanB(int* __restrict__ bsum, int nb) {
    __shared__ int sh[128];
    int t = threadIdx.x;
    int v = (t < nb) ? bsum[t] : 0;
    sh[t] = v;
    __syncthreads();
    for (int off = 1; off < 128; off <<= 1) {
        int add = (t >= off) ? sh[t - off] : 0;
        __syncthreads();
        sh[t] += add;
        __syncthreads();
    }
    if (t < nb) bsum[t] = sh[t] - v;
}

__global__ __launch_bounds__(256) void k_scanC(int* __restrict__ out, const int* __restrict__ bsum, int L) {
    int t = threadIdx.x, b = blockIdx.x;
    int off = bsum[b];
    int base = b * 1024 + t * 4;
#pragma unroll
    for (int j = 0; j < 4; ++j)
        if (base + j < L) out[base + j] += off;
}

// pass-1 scatter: block b writes its edges into its private per-digit runs
// packed elem = (col&255)<<17 | row   (row < 2^17)
__global__ __launch_bounds__(256) void k_scatter1(const int* __restrict__ row, const int* __restrict__ col,
                                                  const int* __restrict__ hoff, unsigned* __restrict__ tmp) {
    __shared__ int lcnt[N_BUCKET];
    int b = blockIdx.x, t = threadIdx.x;
    for (int d = t; d < N_BUCKET; d += 256) lcnt[d] = hoff[d * 256 + b];
    __syncthreads();
    const int base = b * 3125;
    for (int i = t; i < 3125; i += 256) {
        int c = col[base + i];
        int r = row[base + i];
        int p = atomicAdd(&lcnt[c >> 8], 1);
        tmp[p] = ((unsigned)(c & 255) << 17) | (unsigned)r;
    }
}

// pass-2: one block per bucket — counting sort by low 8 bits entirely from a contiguous segment.
// Also emits starts, dinv, rsq (per-col counts are the histogram).
__global__ __launch_bounds__(256) void k_bucket(const unsigned* __restrict__ tmp, const int* __restrict__ hoff,
                                                int* __restrict__ starts, int* __restrict__ csr,
                                                float* __restrict__ dinv, float* __restrict__ rsq) {
    __shared__ int hist[256], sh[256], cur[256];
    int d = blockIdx.x, t = threadIdx.x;
    int s0 = hoff[d * 256];
    int s1 = (d < N_BUCKET - 1) ? hoff[(d + 1) * 256] : N_EDGES;
    int len = s1 - s0;
    hist[t] = 0;
    __syncthreads();
    for (int i = t; i < len; i += 256) atomicAdd(&hist[tmp[s0 + i] >> 17], 1);
    __syncthreads();
    int h = hist[t];
    sh[t] = h;
    __syncthreads();
    for (int off = 1; off < 256; off <<= 1) {
        int add = (t >= off) ? sh[t - off] : 0;
        __syncthreads();
        sh[t] += add;
        __syncthreads();
    }
    int excl = sh[t] - h;
    int colg = d * 256 + t;
    if (colg < N_NODES) {
        starts[colg] = s0 + excl;
        dinv[colg] = rsqrtf((float)h + 1.f);
        rsq[colg]  = sqrtf((float)h + 1.f);
    }
    if (d == N_BUCKET - 1 && t == 0) starts[N_NODES] = N_EDGES;
    cur[t] = s0 + excl;
    __syncthreads();
    for (int i = t; i < len; i += 256) {
        unsigned e = tmp[s0 + i];
        int p = atomicAdd(&cur[e >> 17], 1);
        csr[p] = (int)(e & 0x1FFFFu);
    }
}

// ---------------- weight conversion: fp32 -> k-paired half2 ----------------
__global__ __launch_bounds__(256) void k_wcvt(const float* __restrict__ conv_w, const float* __restrict__ fc1_w,
                                              const float* __restrict__ fc0_w,
                                              unsigned* __restrict__ wh, unsigned* __restrict__ w1h,
                                              unsigned* __restrict__ w0h) {
    int i = blockIdx.x * 256 + threadIdx.x;
    if (i < 3 * 2048) {
        int layer = i >> 11, rem = i & 2047, kp = rem >> 6, c = rem & 63;
        const float* wsrc = conv_w + (size_t)(layer + 1) * 4096;
        wh[i] = pack2u(wsrc[(2 * kp) * 64 + c], wsrc[(2 * kp + 1) * 64 + c]);
        return;
    }
    int j = i - 3 * 2048;
    if (j < 1280) {
        int kp = j / 40, c = j - kp * 40;
        w1h[j] = pack2u(fc1_w[(2 * kp) * 40 + c], fc1_w[(2 * kp + 1) * 40 + c]);
        return;
    }
    int t = j - 1280;
    if (t < 4096) {
        int kp = t >> 6, c = t & 63;
        w0h[t] = pack2u(fc0_w[(2 * kp) * 64 + c], fc0_w[(2 * kp + 1) * 64 + c]);
    }
}

// ---------------- fc0: h_pre0 = fp16(dinv * relu(x @ W0 + b0)), 128 -> 64, dot2 ----------------
__global__ __launch_bounds__(256, 4) void k_fc0(const float* __restrict__ x, const unsigned* __restrict__ w0h,
                                                const float* __restrict__ bias, const float* __restrict__ dinv,
                                                uint2* __restrict__ out) {
    __shared__ unsigned wsh[64 * 64];   // 16KB
    __shared__ unsigned xs2[64 * 65];   // 16.6KB, pad 65
    const float4* x4 = reinterpret_cast<const float4*>(x);
    int tid = threadIdx.x;
    int base = blockIdx.x * 64;
#pragma unroll
    for (int i = 0; i < 4; ++i)
        reinterpret_cast<uint4*>(wsh)[tid + 256 * i] = reinterpret_cast<const uint4*>(w0h)[tid + 256 * i];
#pragma unroll
    for (int j = 0; j < 8; ++j) {
        int f = tid + 256 * j;          // 0..2047
        int ln = f >> 5, c = f & 31;    // c-th float4 of row ln
        float4 v = (base + ln < N_NODES) ? x4[(size_t)(base + ln) * 32 + c] : f4zero();
        xs2[ln * 65 + 2 * c]     = pack2u(v.x, v.y);
        xs2[ln * 65 + 2 * c + 1] = pack2u(v.z, v.w);
    }
    __syncthreads();
    int q = tid & 15, lbase = (tid >> 4) * 4;
    float4 bv = reinterpret_cast<const float4*>(bias)[q];
    float a[4][4];
#pragma unroll
    for (int n = 0; n < 4; ++n) { a[n][0] = bv.x; a[n][1] = bv.y; a[n][2] = bv.z; a[n][3] = bv.w; }
#pragma unroll 4
    for (int kp = 0; kp < 64; ++kp) {
        unsigned xh0 = xs2[(lbase + 0) * 65 + kp];
        unsigned xh1 = xs2[(lbase + 1) * 65 + kp];
        unsigned xh2 = xs2[(lbase + 2) * 65 + kp];
        unsigned xh3 = xs2[(lbase + 3) * 65 + kp];
        uint4 wv = *reinterpret_cast<const uint4*>(&wsh[kp * 64 + q * 4]);
        a[0][0] = fdot2(xh0, wv.x, a[0][0]); a[0][1] = fdot2(xh0, wv.y, a[0][1]);
        a[0][2] = fdot2(xh0, wv.z, a[0][2]); a[0][3] = fdot2(xh0, wv.w, a[0][3]);
        a[1][0] = fdot2(xh1, wv.x, a[1][0]); a[1][1] = fdot2(xh1, wv.y, a[1][1]);
        a[1][2] = fdot2(xh1, wv.z, a[1][2]); a[1][3] = fdot2(xh1, wv.w, a[1][3]);
        a[2][0] = fdot2(xh2, wv.x, a[2][0]); a[2][1] = fdot2(xh2, wv.y, a[2][1]);
        a[2][2] = fdot2(xh2, wv.z, a[2][2]); a[2][3] = fdot2(xh2, wv.w, a[2][3]);
        a[3][0] = fdot2(xh3, wv.x, a[3][0]); a[3][1] = fdot2(xh3, wv.y, a[3][1]);
        a[3][2] = fdot2(xh3, wv.z, a[3][2]); a[3][3] = fdot2(xh3, wv.w, a[3][3]);
    }
#pragma unroll
    for (int n = 0; n < 4; ++n) {
        int nn = base + lbase + n;
        if (nn < N_NODES) {
            float dc = dinv[nn];
            float r0 = dc * fmaxf(a[n][0], 0.f), r1 = dc * fmaxf(a[n][1], 0.f);
            float r2 = dc * fmaxf(a[n][2], 0.f), r3 = dc * fmaxf(a[n][3], 0.f);
            uint2 u; u.x = pack2u(r0, r1); u.y = pack2u(r2, r3);
            out[(size_t)nn * 16 + q] = u;
        }
    }
}

// ---------------- packed fp16 gather (4 pk_fma/edge) with csr prefetch ----------------
__device__ __forceinline__ void gather8h(const uint4* __restrict__ hp, const int* __restrict__ csr,
                                         int s, int e, int q, __half2 acc2[4]) {
    if (s >= e) return;
    int l = e - 1;
    int idx[8];
#pragma unroll
    for (int j = 0; j < 8; ++j) idx[j] = csr[min(s + j, l)];
    for (int p = s; p < e; p += 8) {
        uint4 d[8];
        unsigned msk[8];
#pragma unroll
        for (int j = 0; j < 8; ++j) {
            d[j] = hp[(size_t)idx[j] * 8 + q];
            msk[j] = (p + j <= l) ? 0x3C003C00u : 0u;  // half2{1,1} : {0,0}
        }
        if (p + 8 < e) {
#pragma unroll
            for (int j = 0; j < 8; ++j) idx[j] = csr[min(p + 8 + j, l)];
        }
#pragma unroll
        for (int j = 0; j < 8; ++j) {
            __half2 w2 = *reinterpret_cast<__half2*>(&msk[j]);
            const __half2* h2 = reinterpret_cast<const __half2*>(&d[j]);
            acc2[0] = __hfma2(w2, h2[0], acc2[0]);
            acc2[1] = __hfma2(w2, h2[1], acc2[1]);
            acc2[2] = __hfma2(w2, h2[2], acc2[2]);
            acc2[3] = __hfma2(w2, h2[3], acc2[3]);
        }
    }
}

// ---------------- prop0 ----------------
__global__ __launch_bounds__(256, 6) void k_prop0(const uint4* __restrict__ hp, uint4* __restrict__ x0p,
                                                  const float* __restrict__ dinv,
                                                  const int* __restrict__ starts, const int* __restrict__ csr) {
    int t = blockIdx.x * 256 + threadIdx.x;
    int node = t >> 3, q = t & 7;
    uint4 self = hp[(size_t)node * 8 + q];
    __half2 acc2[4];
    const __half2* sh2 = reinterpret_cast<const __half2*>(&self);
#pragma unroll
    for (int k = 0; k < 4; ++k) acc2[k] = sh2[k];
    gather8h(hp, csr, starts[node], starts[node + 1], q, acc2);
    float dc = dinv[node];
    float accf[8];
    unpack8(*reinterpret_cast<uint4*>(acc2), accf);
    float o[8];
#pragma unroll
    for (int k = 0; k < 8; ++k) o[k] = dc * fmaxf(dc * accf[k], 0.f);
    x0p[(size_t)node * 8 + q] = pack8(o);
}

// ---------------- fused: prop + alpha-combine + conv [+ fc1], all dot2 ----------------
template <bool FINAL>
__global__ __launch_bounds__(256, 6) void k_propconv(
    const uint4* __restrict__ hp_in, const uint4* __restrict__ x0p,
    const float* __restrict__ dinv, const float* __restrict__ rsq,
    const int* __restrict__ starts, const int* __restrict__ csr,
    const unsigned* __restrict__ wh, float beta,
    const unsigned* __restrict__ w1h, const float* __restrict__ b1,
    void* __restrict__ out) {
    __shared__ unsigned ws2[32 * 64];                 // 8KB: paired conv W [kp][c]
    __shared__ unsigned ws12[FINAL ? 32 * 40 : 1];    // 5KB: paired fc1 W (FINAL)

    int tid = threadIdx.x;
    int nl = tid >> 3, q = tid & 7;
    int node = blockIdx.x * 32 + nl;

    // stage weights early (complete under the gather)
    reinterpret_cast<uint4*>(ws2)[tid]       = reinterpret_cast<const uint4*>(wh)[tid];
    reinterpret_cast<uint4*>(ws2)[tid + 256] = reinterpret_cast<const uint4*>(wh)[tid + 256];
    if constexpr (FINAL) {
        reinterpret_cast<uint4*>(ws12)[tid < 320 ? tid : 0] = reinterpret_cast<const uint4*>(w1h)[tid < 320 ? tid : 0];
        if (tid < 64) reinterpret_cast<uint4*>(ws12)[tid + 256] = reinterpret_cast<const uint4*>(w1h)[tid + 256];
    }

    uint4 self = hp_in[(size_t)node * 8 + q];
    __half2 acc2[4];
    const __half2* sh2 = reinterpret_cast<const __half2*>(&self);
#pragma unroll
    for (int k = 0; k < 4; ++k) acc2[k] = sh2[k];
    gather8h(hp_in, csr, starts[node], starts[node + 1], q, acc2);

    float dc = dinv[node];
    float rs = rsq[node];
    float accf[8], xq[8];
    unpack8(*reinterpret_cast<uint4*>(acc2), accf);
    unpack8(x0p[(size_t)node * 8 + q], xq);
    float m[8];
#pragma unroll
    for (int k = 0; k < 8; ++k) m[k] = 0.9f * dc * accf[k] + 0.1f * rs * xq[k];
    unsigned mh[4];
#pragma unroll
    for (int t = 0; t < 4; ++t) mh[t] = pack2u(m[2 * t], m[2 * t + 1]);

    __syncthreads();  // weights visible

    // conv: a[c] = sum_k m[k]*W[k][c] via dot2; m fetched from owner lane via shfl(width 8)
    float a[8] = {0.f, 0.f, 0.f, 0.f, 0.f, 0.f, 0.f, 0.f};
#pragma unroll
    for (int src = 0; src < 8; ++src) {
        unsigned mm[4];
#pragma unroll
        for (int t = 0; t < 4; ++t) mm[t] = (unsigned)__shfl((int)mh[t], src, 8);
#pragma unroll
        for (int t = 0; t < 4; ++t) {
            int kp = src * 4 + t;
            const uint4* wr = reinterpret_cast<const uint4*>(&ws2[kp * 64 + q * 8]);
            uint4 w0 = wr[0], w1 = wr[1];
            a[0] = fdot2(mm[t], w0.x, a[0]); a[1] = fdot2(mm[t], w0.y, a[1]);
            a[2] = fdot2(mm[t], w0.z, a[2]); a[3] = fdot2(mm[t], w0.w, a[3]);
            a[4] = fdot2(mm[t], w1.x, a[4]); a[5] = fdot2(mm[t], w1.y, a[5]);
            a[6] = fdot2(mm[t], w1.z, a[6]); a[7] = fdot2(mm[t], w1.w, a[7]);
        }
    }
    float omb = 1.f - beta;
    float r[8];
#pragma unroll
    for (int k = 0; k < 8; ++k) r[k] = fmaxf(fmaf(omb, m[k], beta * a[k]), 0.f);

    if constexpr (!FINAL) {
        float o[8];
#pragma unroll
        for (int k = 0; k < 8; ++k) o[k] = dc * r[k];
        reinterpret_cast<uint4*>(out)[(size_t)node * 8 + q] = pack8(o);
    } else {
        // fc1 via the same shuffle+dot2 trick (no LDS tile)
        unsigned rh[4];
#pragma unroll
        for (int t = 0; t < 4; ++t) rh[t] = pack2u(r[2 * t], r[2 * t + 1]);
        float acc1[5];
#pragma unroll
        for (int j = 0; j < 5; ++j) acc1[j] = b1[q * 5 + j];
#pragma unroll
        for (int src = 0; src < 8; ++src) {
            unsigned rm[4];
#pragma unroll
            for (int t = 0; t < 4; ++t) rm[t] = (unsigned)__shfl((int)rh[t], src, 8);
#pragma unroll
            for (int t = 0; t < 4; ++t) {
                int kp = src * 4 + t;
                const unsigned* wr = &ws12[kp * 40 + q * 5];
#pragma unroll
                for (int j = 0; j < 5; ++j) acc1[j] = fdot2(rm[t], wr[j], acc1[j]);
            }
        }
        float* o = reinterpret_cast<float*>(out) + (size_t)node * 40 + q * 5;
#pragma unroll
        for (int j = 0; j < 5; ++j) o[j] = acc1[j];
    }
}

// ---------------- launch ----------------

extern "C" void kernel_launch(void* const* d_in, const int* in_sizes, int n_in,
                              void* d_out, int out_size, void* d_ws, size_t ws_size,
                              hipStream_t stream) {
    const float* x      = (const float*)d_in[0];
    const int*   ei     = (const int*)d_in[1];
    const float* fc0_w  = (const float*)d_in[2];
    const float* fc0_b  = (const float*)d_in[3];
    const float* fc1_w  = (const float*)d_in[4];
    const float* fc1_b  = (const float*)d_in[5];
    const float* conv_w = (const float*)d_in[6];
    const int* row = ei;
    const int* col = ei + N_EDGES;

    char* ws = (char*)d_ws;
    size_t off = 0;
    auto alloc = [&](size_t bytes) -> void* {
        void* p = ws + off;
        off += (bytes + 255) & ~(size_t)255;
        return p;
    };
    float*    dinv   = (float*)alloc((size_t)N_NODES * 4);
    float*    rsq    = (float*)alloc((size_t)N_NODES * 4);
    int*      starts = (int*)alloc((size_t)(N_NODES + 1) * 4);
    int*      histT  = (int*)alloc((size_t)L_HIST * 4);
    int*      hoff   = (int*)alloc((size_t)L_HIST * 4);
    int*      bsum   = (int*)alloc(128 * 4);
    unsigned* tmp    = (unsigned*)alloc((size_t)N_EDGES * 4);
    int*      csr    = (int*)alloc((size_t)N_EDGES * 4);
    unsigned* wh     = (unsigned*)alloc(3 * 2048 * 4);
    unsigned* w1h    = (unsigned*)alloc(1280 * 4);
    unsigned* w0h    = (unsigned*)alloc(4096 * 4);
    uint4*    hp0    = (uint4*)alloc((size_t)N_NODES * 128);
    uint4*    x0p    = (uint4*)alloc((size_t)N_NODES * 128);
    uint4*    hpA    = (uint4*)alloc((size_t)N_NODES * 128);
    uint4*    hpB    = (uint4*)alloc((size_t)N_NODES * 128);
    if (off > ws_size) return;

    const int NBH = (L_HIST + 1023) / 1024;           // 98
    const int GMM = (N_NODES + 63) / 64;              // 1563 (fc0)
    const int GP  = (N_NODES * 8) / 256;              // 3125 (prop0)
    const int GPC = N_NODES / 32;                     // 3125 (propconv)

    // weight conversion (independent) + CSR bucket-sort build
    k_wcvt<<<45, 256, 0, stream>>>(conv_w, fc1_w, fc0_w, wh, w1h, w0h);
    k_hist<<<256, 256, 0, stream>>>(col, histT);
    k_scanA<<<NBH, 256, 0, stream>>>(histT, hoff, bsum, L_HIST);
    k_scanB<<<1, 128, 0, stream>>>(bsum, NBH);
    k_scanC<<<NBH, 256, 0, stream>>>(hoff, bsum, L_HIST);
    k_scatter1<<<256, 256, 0, stream>>>(row, col, hoff, tmp);
    k_bucket<<<N_BUCKET, 256, 0, stream>>>(tmp, hoff, starts, csr, dinv, rsq);

    // fc0 -> hp0; prop0 -> x0p
    k_fc0<<<GMM, 256, 0, stream>>>(x, w0h, fc0_b, dinv, (uint2*)hp0);
    k_prop0<<<GP, 256, 0, stream>>>(hp0, x0p, dinv, starts, csr);

    const float betas[4] = {0.f, logf(0.5f / 2.f + 1.f), logf(0.5f / 3.f + 1.f), logf(0.5f / 4.f + 1.f)};

    // layer 1: x0p -> hpA ; layer 2: hpA -> hpB ; layer 3 (+fc1): hpB -> d_out
    k_propconv<false><<<GPC, 256, 0, stream>>>(x0p, x0p, dinv, rsq, starts, csr,
                                               wh + 0 * 2048, betas[1], nullptr, nullptr, hpA);
    k_propconv<false><<<GPC, 256, 0, stream>>>(hpA, x0p, dinv, rsq, starts, csr,
                                               wh + 1 * 2048, betas[2], nullptr, nullptr, hpB);
    k_propconv<true><<<GPC, 256, 0, stream>>>(hpB, x0p, dinv, rsq, starts, csr,
                                              wh + 2 * 2048, betas[3], w1h, fc1_b, d_out);
}